// Round 8
// baseline (120.734 us; speedup 1.0000x reference)
//
#include <hip/hip_runtime.h>
#include <math.h>

#define BATCH 2
#define CCH 64      // C
#define HL 128
#define WL 128
#define HH 256
#define WH 256
#define CFCH 256
#define CIN 72

// workspace layout (float offsets) — compact
constexpr long WS_AL   = 0;                     // a_l   (B*C = 128)
constexpr long WS_BL   = 128;                   // bb_l
constexpr long WS_AH   = 256;                   // a_h
constexpr long WS_BH   = 384;                   // bb_h
constexpr long WS_OFFL = 512;                   // 2*32*128*128 = 1048576
constexpr long WS_DSL  = WS_OFFL + 1048576;
constexpr long WS_OFFH = WS_DSL + 1048576;      // 2*8*256*256 = 1048576
constexpr long WS_DSH  = WS_OFFH + 1048576;
constexpr long WS_CRD  = WS_DSH + 1048576;      // float2[2*16*128*128] = 1048576 floats
constexpr long WS_PART = WS_CRD + 1048576;      // 32 groups * 64 slices * 2

// ---------------- K1a: partial sums over 8192-element slices ----------------
__global__ void k_stats1(const float* __restrict__ xl, const float* __restrict__ xh,
                         float* __restrict__ ws) {
  int blk = blockIdx.x;
  const float* x;
  long base;
  int gg, slice;
  if (blk < 256) {
    int g = blk >> 4; slice = blk & 15;
    x = xl; gg = g;
    base = (long)g * 8 * (HL * WL) + (long)slice * 8192;
  } else {
    int id = blk - 256;
    int g = id >> 6; slice = id & 63;
    x = xh; gg = 16 + g;
    base = (long)g * 8 * (HH * WH) + (long)slice * 8192;
  }
  const float4* p = (const float4*)(x + base);
  float s = 0.f, s2 = 0.f;
  #pragma unroll
  for (int k = 0; k < 8; k++) {
    float4 v = p[threadIdx.x + k * 256];
    s  += v.x + v.y + v.z + v.w;
    s2 += v.x * v.x + v.y * v.y + v.z * v.z + v.w * v.w;
  }
  __shared__ float sh1[256], sh2[256];
  sh1[threadIdx.x] = s; sh2[threadIdx.x] = s2;
  __syncthreads();
  for (int off = 128; off > 0; off >>= 1) {
    if (threadIdx.x < off) {
      sh1[threadIdx.x] += sh1[threadIdx.x + off];
      sh2[threadIdx.x] += sh2[threadIdx.x + off];
    }
    __syncthreads();
  }
  if (threadIdx.x == 0) {
    ws[WS_PART + (gg * 64 + slice) * 2]     = sh1[0];
    ws[WS_PART + (gg * 64 + slice) * 2 + 1] = sh2[0];
  }
}

// ---------------- K1b: finalize per-channel affine coefficients -------------
__global__ void k_stats2(const float* __restrict__ gwl, const float* __restrict__ gbl,
                         const float* __restrict__ gwh, const float* __restrict__ gbh,
                         float* __restrict__ ws) {
  int blk = blockIdx.x;          // 0..31
  bool high = blk >= 16;
  int id = blk & 15;
  int b = id >> 3, g = id & 7;
  int gg = high ? 16 + id : id;
  int nsl = high ? 64 : 16;
  long n = high ? (long)8 * HH * WH : (long)8 * HL * WL;
  float s = 0.f, s2 = 0.f;
  for (int i = threadIdx.x; i < nsl; i += 64) {
    s  += ws[WS_PART + (gg * 64 + i) * 2];
    s2 += ws[WS_PART + (gg * 64 + i) * 2 + 1];
  }
  for (int off = 32; off > 0; off >>= 1) {
    s  += __shfl_down(s, off);
    s2 += __shfl_down(s2, off);
  }
  __shared__ float shm[2];
  if (threadIdx.x == 0) { shm[0] = s; shm[1] = s2; }
  __syncthreads();
  if (threadIdx.x < 8) {
    float mean = shm[0] / (float)n;
    float var  = shm[1] / (float)n - mean * mean;
    float inv  = rsqrtf(var + 1e-5f);
    int c = g * 8 + threadIdx.x;
    const float* gw = high ? gwh : gwl;
    const float* gb = high ? gbh : gbl;
    float a  = gw[c] * inv;
    float bb = gb[c] - mean * a;
    float* abase = ws + (high ? WS_AH : WS_AL);
    abase[b * CCH + c] = a;
    abase[128 + b * CCH + c] = bb;
  }
}

// ---------------- K3/K4: fused sim + conv1x1_bn heads ----------------------
template<int HSZ, int WSZ, int NOUT>
__global__ __launch_bounds__(512) void k_head(
                       const float* __restrict__ x,
                       const float* __restrict__ w_off, const float* __restrict__ w_ds,
                       const float* __restrict__ s_off, const float* __restrict__ b_off,
                       const float* __restrict__ s_ds,  const float* __restrict__ b_ds,
                       const float* __restrict__ acoef, const float* __restrict__ bcoef,
                       float* __restrict__ out_off, float* __restrict__ out_ds) {
  constexpr int HW   = HSZ * WSZ;
  constexpr int half = NOUT / 2;
  constexpr int PER  = NOUT / 8;
  __shared__ float wsm[NOUT * CIN];
  __shared__ float xc[CCH * 64];
  __shared__ float psum[8 * 64];
  __shared__ float sims[8 * 64];
  __shared__ float asm_[CCH], bsm_[CCH];

  int tid = threadIdx.x;
  int px = tid & 63;
  int t  = tid >> 6;                 // wave index 0..7, wave-uniform
  int gpix = blockIdx.x * 64 + px;
  int xq = gpix % WSZ;
  int yq = (gpix / WSZ) % HSZ;
  int bq = gpix / (WSZ * HSZ);       // uniform per block

  for (int i = tid; i < NOUT * CIN; i += 512) {
    int o = i / CIN, c = i % CIN;
    wsm[i] = (o < half) ? w_off[o * CIN + c] : w_ds[(o - half) * CIN + c];
  }
  if (tid < CCH)            asm_[tid] = acoef[bq * CCH + tid];
  else if (tid < 2 * CCH)   bsm_[tid - CCH] = bcoef[bq * CCH + tid - CCH];
  __syncthreads();

  const float* ptr = x + ((long)(bq * CCH)) * HW + yq * WSZ + xq;

  // phase 0: center tile + sumsq partials
  {
    float ss = 0.f;
    #pragma unroll
    for (int k = 0; k < 8; k++) {
      int c = t * 8 + k;
      float v = fmaf(asm_[c], ptr[(long)c * HW], bsm_[c]);
      xc[c * 64 + px] = v;
      ss += v * v;
    }
    psum[t * 64 + px] = ss;
  }
  __syncthreads();

  // phase 1: neighbor t
  {
    const int dyv[8] = {-2,-2,-2, 0, 0, 2, 2, 2};
    const int dxv[8] = {-2, 0, 2,-2, 2,-2, 0, 2};
    int dy = dyv[t], dx = dxv[t];
    int yn = yq + dy;                // uniform
    int xn = xq + dx;                // per-lane
    bool ok = (yn >= 0 && yn < HSZ && xn >= 0 && xn < WSZ);
    float dot = 0.f, nbq = 0.f;
    if (ok) {
      const float* nptr = ptr + (long)dy * WSZ + dx;
      #pragma unroll 16
      for (int c = 0; c < CCH; c++) {
        float nb = fmaf(asm_[c], nptr[(long)c * HW], bsm_[c]);
        float xv = xc[c * 64 + px];
        dot += xv * nb;
        nbq += nb * nb;
      }
    }
    float cs = 0.f;
    #pragma unroll
    for (int tt = 0; tt < 8; tt++) cs += psum[tt * 64 + px];
    float cnc = sqrtf(cs);
    sims[t * 64 + px] = dot / fmaxf(cnc * sqrtf(nbq), 1e-8f);
  }
  __syncthreads();

  // phase 2: conv outputs for this wave
  {
    float sv[8];
    #pragma unroll
    for (int j = 0; j < 8; j++) sv[j] = sims[j * 64 + px];
    float acc[PER];
    #pragma unroll
    for (int ol = 0; ol < PER; ol++) acc[ol] = 0.f;
    int o0 = t * PER;
    #pragma unroll 4
    for (int c = 0; c < CCH; c += 4) {
      float x0v = xc[(c + 0) * 64 + px];
      float x1v = xc[(c + 1) * 64 + px];
      float x2v = xc[(c + 2) * 64 + px];
      float x3v = xc[(c + 3) * 64 + px];
      #pragma unroll
      for (int ol = 0; ol < PER; ol++) {
        const float4 w4 = *(const float4*)&wsm[(o0 + ol) * CIN + c];
        acc[ol] += w4.x * x0v + w4.y * x1v + w4.z * x2v + w4.w * x3v;
      }
    }
    #pragma unroll
    for (int ol = 0; ol < PER; ol++) {
      const float4 wa = *(const float4*)&wsm[(o0 + ol) * CIN + 64];
      const float4 wb = *(const float4*)&wsm[(o0 + ol) * CIN + 68];
      acc[ol] += wa.x * sv[0] + wa.y * sv[1] + wa.z * sv[2] + wa.w * sv[3]
               + wb.x * sv[4] + wb.y * sv[5] + wb.z * sv[6] + wb.w * sv[7];
    }
    #pragma unroll
    for (int ol = 0; ol < PER; ol++) {
      int o = o0 + ol;
      float v;
      float* dst;
      int oo;
      if (o < half) { v = acc[ol] * s_off[o] + b_off[o];             dst = out_off; oo = o; }
      else          { v = acc[ol] * s_ds[o - half] + b_ds[o - half]; dst = out_ds;  oo = o - half; }
      dst[((long)(bq * half + oo)) * HW + yq * WSZ + xq] = v;
    }
  }
}

// ---------------- K5: combine -> packed clipped sample coords --------------
// one thread per (b,sub,y,x); writes float2 (gx,gy) ready for bilinear.
__global__ __launch_bounds__(256) void k_combine(float* __restrict__ ws) {
  int idx = blockIdx.x * blockDim.x + threadIdx.x;   // B*16*128*128 = 524288
  int x = idx & 127;
  int y = (idx >> 7) & 127;
  int sub = (idx >> 14) & 15;
  int b = idx >> 18;
  int sdx = sub & 1, sdy = (sub >> 1) & 1;

  const float* offl = ws + WS_OFFL;
  const float* dsl  = ws + WS_DSL;
  const float* offh = ws + WS_OFFH;
  const float* dsh  = ws + WS_DSH;

  int lidx = idx + b * (16 * HL * WL);               // channel sub (of 32)
  float ol0 = offl[lidx],               dl0 = dsl[lidx];
  float ol1 = offl[lidx + 16 * HL * WL], dl1 = dsl[lidx + 16 * HL * WL];
  int Y = 2 * y + sdy, X = 2 * x + sdx;
  long h0 = ((long)(b * 8 + (sub >> 2)) * HH + Y) * WH + X;
  long h1 = h0 + (long)4 * HH * WH;
  float oh0 = offh[h0], dh0 = dsh[h0];
  float oh1 = offh[h1], dh1 = dsh[h1];
  float gate0 = 1.f / (1.f + expf(-(dl0 + dh0)));
  float gate1 = 1.f / (1.f + expf(-(dl1 + dh1)));
  float offx = (ol0 + oh0) * gate0 + (sdx ? 0.25f : -0.25f);
  float offy = (ol1 + oh1) * gate1 + (sdy ? 0.25f : -0.25f);
  float gx = fminf(fmaxf((float)x + offx, 0.f), (float)(WL - 1));
  float gy = fminf(fmaxf((float)y + offy, 0.f), (float)(HL - 1));
  float2* crd = (float2*)(ws + WS_CRD);
  crd[idx] = float2{gx, gy};
}

// ---------------- K6: bilinear sampler, 64 channels per thread -------------
// Explicit 8-channel batches: 16 independent float2 loads in flight per batch
// (forces ~48 VGPRs instead of 12 -> deep MLP instead of serialized chains).
__global__ __launch_bounds__(256) void k_sample(const float* __restrict__ feat,
                                                const float* __restrict__ ws,
                                                float* __restrict__ out) {
  // XCD-aware bijective swizzle: 2048 blocks, 8 XCDs, 256 blocks each ->
  // each XCD owns one contiguous (b,g) slab (64 feat planes = 4.2 MB, L2-fit).
  int bid = (blockIdx.x & 7) * 256 + (blockIdx.x >> 3);
  long idx = (long)bid * 256 + threadIdx.x;
  int X = idx & 255;
  int Y = (idx >> 8) & 255;
  int g = (idx >> 16) & 3;
  int b = (int)(idx >> 18);
  int x = X >> 1, sdx = X & 1, y = Y >> 1, sdy = Y & 1;
  int sub = 4 * g + 2 * sdy + sdx;

  const float2* crd = (const float2*)(ws + WS_CRD);
  int cidx = b * (16 * HL * WL) + sub * (HL * WL) + y * WL + x;
  float2 cc = crd[cidx];
  float gx = cc.x, gy = cc.y;

  float fx0 = floorf(gx), fy0 = floorf(gy);
  int x0 = (int)fx0, y0 = (int)fy0;
  float wx = gx - fx0, wy = gy - fy0;
  // edge adjust: keeps x0+wx / y0+wy invariant, makes x1=x0+1, y1=y0+1 valid
  if (x0 >= WL - 1) { x0 = WL - 2; wx = 1.f; }
  if (y0 >= HL - 1) { y0 = HL - 2; wy = 1.f; }
  int o00 = y0 * WL + x0;
  float w00 = (1.f - wx) * (1.f - wy), w01 = wx * (1.f - wy);
  float w10 = (1.f - wx) * wy,         w11 = wx * wy;

  const float* plane = feat + ((long)(b * CFCH + g * 64)) * (HL * WL) + o00;
  float* optr = out + (((long)(b * CFCH + g * 64)) * HH + Y) * WH + X;
  #pragma unroll 1
  for (int bb = 0; bb < 8; bb++) {
    float2 r0[8], r1[8];
    #pragma unroll
    for (int k = 0; k < 8; k++) {
      const float* p = plane + (long)(bb * 8 + k) * (HL * WL);
      r0[k] = *(const float2*)(p);
      r1[k] = *(const float2*)(p + WL);
    }
    #pragma unroll
    for (int k = 0; k < 8; k++) {
      float v = r0[k].x * w00 + r0[k].y * w01 + r1[k].x * w10 + r1[k].y * w11;
      optr[(long)(bb * 8 + k) * (HH * WH)] = v;
    }
  }
}

extern "C" void kernel_launch(void* const* d_in, const int* in_sizes, int n_in,
                              void* d_out, int out_size, void* d_ws, size_t ws_size,
                              hipStream_t stream) {
  const float* x_l     = (const float*)d_in[0];
  const float* x_h     = (const float*)d_in[1];
  const float* feat    = (const float*)d_in[2];
  const float* gn_l_w  = (const float*)d_in[3];
  const float* gn_l_b  = (const float*)d_in[4];
  const float* gn_h_w  = (const float*)d_in[5];
  const float* gn_h_b  = (const float*)d_in[6];
  const float* w_off   = (const float*)d_in[7];
  const float* s_off   = (const float*)d_in[8];
  const float* b_off   = (const float*)d_in[9];
  const float* w_off_h = (const float*)d_in[10];
  const float* s_off_h = (const float*)d_in[11];
  const float* b_off_h = (const float*)d_in[12];
  const float* w_ds    = (const float*)d_in[13];
  const float* s_ds    = (const float*)d_in[14];
  const float* b_ds    = (const float*)d_in[15];
  const float* w_ds_h  = (const float*)d_in[16];
  const float* s_ds_h  = (const float*)d_in[17];
  const float* b_ds_h  = (const float*)d_in[18];
  float* ws  = (float*)d_ws;
  float* out = (float*)d_out;

  k_stats1<<<1280, 256, 0, stream>>>(x_l, x_h, ws);
  k_stats2<<<32, 64, 0, stream>>>(gn_l_w, gn_l_b, gn_h_w, gn_h_b, ws);
  k_head<HL, WL, 64><<<(BATCH * HL * WL) / 64, 512, 0, stream>>>(
      x_l, w_off, w_ds, s_off, b_off, s_ds, b_ds,
      ws + WS_AL, ws + WS_BL, ws + WS_OFFL, ws + WS_DSL);
  k_head<HH, WH, 16><<<(BATCH * HH * WH) / 64, 512, 0, stream>>>(
      x_h, w_off_h, w_ds_h, s_off_h, b_off_h, s_ds_h, b_ds_h,
      ws + WS_AH, ws + WS_BH, ws + WS_OFFH, ws + WS_DSH);
  k_combine<<<(BATCH * 16 * HL * WL) / 256, 256, 0, stream>>>(ws);
  k_sample<<<2048, 256, 0, stream>>>(feat, ws, out);
}

// Round 9
// 99.246 us; speedup vs baseline: 1.2165x; 1.2165x over previous
//
#include <hip/hip_runtime.h>
#include <math.h>

#define BATCH 2
#define CCH 64      // C
#define HL 128
#define WL 128
#define HH 256
#define WH 256
#define CFCH 256
#define CIN 72

// workspace layout (float offsets) — compact
constexpr long WS_AL   = 0;                     // a_l   (B*C = 128)
constexpr long WS_BL   = 128;                   // bb_l
constexpr long WS_AH   = 256;                   // a_h
constexpr long WS_BH   = 384;                   // bb_h
constexpr long WS_OFFL = 512;                   // 2*32*128*128 = 1048576
constexpr long WS_DSL  = WS_OFFL + 1048576;
constexpr long WS_OFFH = WS_DSL + 1048576;      // 2*8*256*256 = 1048576
constexpr long WS_DSH  = WS_OFFH + 1048576;
constexpr long WS_CRD  = WS_DSH + 1048576;      // float2[2*16*128*128] = 1048576 floats
constexpr long WS_PART = WS_CRD + 1048576;      // 32 groups * 64 slices * 2

// ---------------- K1a: partial sums over 8192-element slices ----------------
__global__ void k_stats1(const float* __restrict__ xl, const float* __restrict__ xh,
                         float* __restrict__ ws) {
  int blk = blockIdx.x;
  const float* x;
  long base;
  int gg, slice;
  if (blk < 256) {
    int g = blk >> 4; slice = blk & 15;
    x = xl; gg = g;
    base = (long)g * 8 * (HL * WL) + (long)slice * 8192;
  } else {
    int id = blk - 256;
    int g = id >> 6; slice = id & 63;
    x = xh; gg = 16 + g;
    base = (long)g * 8 * (HH * WH) + (long)slice * 8192;
  }
  const float4* p = (const float4*)(x + base);
  float s = 0.f, s2 = 0.f;
  #pragma unroll
  for (int k = 0; k < 8; k++) {
    float4 v = p[threadIdx.x + k * 256];
    s  += v.x + v.y + v.z + v.w;
    s2 += v.x * v.x + v.y * v.y + v.z * v.z + v.w * v.w;
  }
  __shared__ float sh1[256], sh2[256];
  sh1[threadIdx.x] = s; sh2[threadIdx.x] = s2;
  __syncthreads();
  for (int off = 128; off > 0; off >>= 1) {
    if (threadIdx.x < off) {
      sh1[threadIdx.x] += sh1[threadIdx.x + off];
      sh2[threadIdx.x] += sh2[threadIdx.x + off];
    }
    __syncthreads();
  }
  if (threadIdx.x == 0) {
    ws[WS_PART + (gg * 64 + slice) * 2]     = sh1[0];
    ws[WS_PART + (gg * 64 + slice) * 2 + 1] = sh2[0];
  }
}

// ---------------- K1b: finalize per-channel affine coefficients -------------
__global__ void k_stats2(const float* __restrict__ gwl, const float* __restrict__ gbl,
                         const float* __restrict__ gwh, const float* __restrict__ gbh,
                         float* __restrict__ ws) {
  int blk = blockIdx.x;          // 0..31
  bool high = blk >= 16;
  int id = blk & 15;
  int b = id >> 3, g = id & 7;
  int gg = high ? 16 + id : id;
  int nsl = high ? 64 : 16;
  long n = high ? (long)8 * HH * WH : (long)8 * HL * WL;
  float s = 0.f, s2 = 0.f;
  for (int i = threadIdx.x; i < nsl; i += 64) {
    s  += ws[WS_PART + (gg * 64 + i) * 2];
    s2 += ws[WS_PART + (gg * 64 + i) * 2 + 1];
  }
  for (int off = 32; off > 0; off >>= 1) {
    s  += __shfl_down(s, off);
    s2 += __shfl_down(s2, off);
  }
  __shared__ float shm[2];
  if (threadIdx.x == 0) { shm[0] = s; shm[1] = s2; }
  __syncthreads();
  if (threadIdx.x < 8) {
    float mean = shm[0] / (float)n;
    float var  = shm[1] / (float)n - mean * mean;
    float inv  = rsqrtf(var + 1e-5f);
    int c = g * 8 + threadIdx.x;
    const float* gw = high ? gwh : gwl;
    const float* gb = high ? gbh : gbl;
    float a  = gw[c] * inv;
    float bb = gb[c] - mean * a;
    float* abase = ws + (high ? WS_AH : WS_AL);
    abase[b * CCH + c] = a;
    abase[128 + b * CCH + c] = bb;
  }
}

// ---------------- K3/K4: fused sim + conv1x1_bn heads ----------------------
template<int HSZ, int WSZ, int NOUT>
__global__ __launch_bounds__(512) void k_head(
                       const float* __restrict__ x,
                       const float* __restrict__ w_off, const float* __restrict__ w_ds,
                       const float* __restrict__ s_off, const float* __restrict__ b_off,
                       const float* __restrict__ s_ds,  const float* __restrict__ b_ds,
                       const float* __restrict__ acoef, const float* __restrict__ bcoef,
                       float* __restrict__ out_off, float* __restrict__ out_ds) {
  constexpr int HW   = HSZ * WSZ;
  constexpr int half = NOUT / 2;
  constexpr int PER  = NOUT / 8;
  __shared__ float wsm[NOUT * CIN];
  __shared__ float xc[CCH * 64];
  __shared__ float psum[8 * 64];
  __shared__ float sims[8 * 64];
  __shared__ float asm_[CCH], bsm_[CCH];

  int tid = threadIdx.x;
  int px = tid & 63;
  int t  = tid >> 6;                 // wave index 0..7, wave-uniform
  int gpix = blockIdx.x * 64 + px;
  int xq = gpix % WSZ;
  int yq = (gpix / WSZ) % HSZ;
  int bq = gpix / (WSZ * HSZ);       // uniform per block

  for (int i = tid; i < NOUT * CIN; i += 512) {
    int o = i / CIN, c = i % CIN;
    wsm[i] = (o < half) ? w_off[o * CIN + c] : w_ds[(o - half) * CIN + c];
  }
  if (tid < CCH)            asm_[tid] = acoef[bq * CCH + tid];
  else if (tid < 2 * CCH)   bsm_[tid - CCH] = bcoef[bq * CCH + tid - CCH];
  __syncthreads();

  const float* ptr = x + ((long)(bq * CCH)) * HW + yq * WSZ + xq;

  // phase 0: center tile + sumsq partials
  {
    float ss = 0.f;
    #pragma unroll
    for (int k = 0; k < 8; k++) {
      int c = t * 8 + k;
      float v = fmaf(asm_[c], ptr[(long)c * HW], bsm_[c]);
      xc[c * 64 + px] = v;
      ss += v * v;
    }
    psum[t * 64 + px] = ss;
  }
  __syncthreads();

  // phase 1: neighbor t
  {
    const int dyv[8] = {-2,-2,-2, 0, 0, 2, 2, 2};
    const int dxv[8] = {-2, 0, 2,-2, 2,-2, 0, 2};
    int dy = dyv[t], dx = dxv[t];
    int yn = yq + dy;                // uniform
    int xn = xq + dx;                // per-lane
    bool ok = (yn >= 0 && yn < HSZ && xn >= 0 && xn < WSZ);
    float dot = 0.f, nbq = 0.f;
    if (ok) {
      const float* nptr = ptr + (long)dy * WSZ + dx;
      #pragma unroll 16
      for (int c = 0; c < CCH; c++) {
        float nb = fmaf(asm_[c], nptr[(long)c * HW], bsm_[c]);
        float xv = xc[c * 64 + px];
        dot += xv * nb;
        nbq += nb * nb;
      }
    }
    float cs = 0.f;
    #pragma unroll
    for (int tt = 0; tt < 8; tt++) cs += psum[tt * 64 + px];
    float cnc = sqrtf(cs);
    sims[t * 64 + px] = dot / fmaxf(cnc * sqrtf(nbq), 1e-8f);
  }
  __syncthreads();

  // phase 2: conv outputs for this wave
  {
    float sv[8];
    #pragma unroll
    for (int j = 0; j < 8; j++) sv[j] = sims[j * 64 + px];
    float acc[PER];
    #pragma unroll
    for (int ol = 0; ol < PER; ol++) acc[ol] = 0.f;
    int o0 = t * PER;
    #pragma unroll 4
    for (int c = 0; c < CCH; c += 4) {
      float x0v = xc[(c + 0) * 64 + px];
      float x1v = xc[(c + 1) * 64 + px];
      float x2v = xc[(c + 2) * 64 + px];
      float x3v = xc[(c + 3) * 64 + px];
      #pragma unroll
      for (int ol = 0; ol < PER; ol++) {
        const float4 w4 = *(const float4*)&wsm[(o0 + ol) * CIN + c];
        acc[ol] += w4.x * x0v + w4.y * x1v + w4.z * x2v + w4.w * x3v;
      }
    }
    #pragma unroll
    for (int ol = 0; ol < PER; ol++) {
      const float4 wa = *(const float4*)&wsm[(o0 + ol) * CIN + 64];
      const float4 wb = *(const float4*)&wsm[(o0 + ol) * CIN + 68];
      acc[ol] += wa.x * sv[0] + wa.y * sv[1] + wa.z * sv[2] + wa.w * sv[3]
               + wb.x * sv[4] + wb.y * sv[5] + wb.z * sv[6] + wb.w * sv[7];
    }
    #pragma unroll
    for (int ol = 0; ol < PER; ol++) {
      int o = o0 + ol;
      float v;
      float* dst;
      int oo;
      if (o < half) { v = acc[ol] * s_off[o] + b_off[o];             dst = out_off; oo = o; }
      else          { v = acc[ol] * s_ds[o - half] + b_ds[o - half]; dst = out_ds;  oo = o - half; }
      dst[((long)(bq * half + oo)) * HW + yq * WSZ + xq] = v;
    }
  }
}

// ---------------- K5: combine -> packed clipped sample coords --------------
// one thread per (b,sub,y,x); writes float2 (gx,gy) ready for bilinear.
__global__ __launch_bounds__(256) void k_combine(float* __restrict__ ws) {
  int idx = blockIdx.x * blockDim.x + threadIdx.x;   // B*16*128*128 = 524288
  int x = idx & 127;
  int y = (idx >> 7) & 127;
  int sub = (idx >> 14) & 15;
  int b = idx >> 18;
  int sdx = sub & 1, sdy = (sub >> 1) & 1;

  const float* offl = ws + WS_OFFL;
  const float* dsl  = ws + WS_DSL;
  const float* offh = ws + WS_OFFH;
  const float* dsh  = ws + WS_DSH;

  int lidx = idx + b * (16 * HL * WL);               // channel sub (of 32)
  float ol0 = offl[lidx],               dl0 = dsl[lidx];
  float ol1 = offl[lidx + 16 * HL * WL], dl1 = dsl[lidx + 16 * HL * WL];
  int Y = 2 * y + sdy, X = 2 * x + sdx;
  long h0 = ((long)(b * 8 + (sub >> 2)) * HH + Y) * WH + X;
  long h1 = h0 + (long)4 * HH * WH;
  float oh0 = offh[h0], dh0 = dsh[h0];
  float oh1 = offh[h1], dh1 = dsh[h1];
  float gate0 = 1.f / (1.f + expf(-(dl0 + dh0)));
  float gate1 = 1.f / (1.f + expf(-(dl1 + dh1)));
  float offx = (ol0 + oh0) * gate0 + (sdx ? 0.25f : -0.25f);
  float offy = (ol1 + oh1) * gate1 + (sdy ? 0.25f : -0.25f);
  float gx = fminf(fmaxf((float)x + offx, 0.f), (float)(WL - 1));
  float gy = fminf(fmaxf((float)y + offy, 0.f), (float)(HL - 1));
  float2* crd = (float2*)(ws + WS_CRD);
  crd[idx] = float2{gx, gy};
}

// ---------------- K6: LDS-staged bilinear sampler --------------------------
// block = (b,g,y): output rows Y=2y,2y+1, all X, 64 channels.
// 8 waves; wave w privately stages channel (chunk*8+w)'s rows y-1..y+2 into
// its own LDS region (global->reg->LDS, next chunk prefetched during compute),
// then samples from LDS. No __syncthreads needed (wave-private regions, DS
// pipe is in-order per wave). Outlier coords (|offy|>~1) take an exact
// global-gather fallback per lane (rare; execz-skipped).
__global__ __launch_bounds__(512, 6) void k_sample(const float* __restrict__ feat,
                                                   const float* __restrict__ ws,
                                                   float* __restrict__ out) {
  __shared__ float sbuf[8 * 512];   // 16 KB: [wave][4 rows][128]
  // XCD swizzle: 1024 blocks, 8 XCDs -> each XCD owns one (b,g) feat slab.
  int bid = (blockIdx.x & 7) * 128 + (blockIdx.x >> 3);
  int y = bid & 127;
  int g = (bid >> 7) & 3;
  int b = bid >> 9;
  int w = threadIdx.x >> 6;         // wave id = local channel, uniform
  int l = threadIdx.x & 63;         // lane = X-group (4 consecutive X)

  // ---- coords: 8 sets (Yp in {0,1}, j in {0..3}), reused for all channels
  const float2* crd = (const float2*)(ws + WS_CRD);
  int   pack[8];
  float wxa[8], wya[8];
  bool fb = false;
  #pragma unroll
  for (int Yp = 0; Yp < 2; Yp++) {
    #pragma unroll
    for (int j = 0; j < 4; j++) {
      int xx = 2 * l + (j >> 1);
      int sub = 4 * g + 2 * Yp + (j & 1);
      float2 cc = crd[((long)(b * 16 + sub)) * (HL * WL) + y * WL + xx];
      float gx = cc.x, gy = cc.y;
      float fx0 = floorf(gx), fy0 = floorf(gy);
      int x0 = (int)fx0, y0 = (int)fy0;
      float wx = gx - fx0, wy = gy - fy0;
      if (x0 >= WL - 1) { x0 = WL - 2; wx = 1.f; }
      if (y0 >= HL - 1) { y0 = HL - 2; wy = 1.f; }
      fb = fb || (y0 < y - 1) || (y0 > y + 1);
      pack[Yp * 4 + j] = y0 * WL + x0;
      wxa[Yp * 4 + j] = wx;
      wya[Yp * 4 + j] = wy;
    }
  }
  int ladj = w * 512 + (1 - y) * 128;    // lds idx = pack + ladj

  // ---- staging addresses (wave w stages its own channel)
  int row0 = l >> 5;                     // 0/1
  int row1 = 2 + row0;                   // 2/3
  int fr0 = min(max(y - 1 + row0, 0), HL - 1);
  int fr1 = min(max(y - 1 + row1, 0), HL - 1);
  int x4 = (l & 31) * 4;
  long cbase = (long)(b * CFCH + g * 64 + w);
  const float* ps0 = feat + (cbase * HL + fr0) * WL + x4;
  const float* ps1 = feat + (cbase * HL + fr1) * WL + x4;
  const float* pg  = feat + cbase * (HL * WL);
  int s0 = w * 512 + row0 * 128 + x4;
  int s1 = w * 512 + row1 * 128 + x4;
  float* po0 = out + (cbase * HH + 2 * y) * WH + 4 * l;
  float* po1 = po0 + WH;
  const long CSTEP  = (long)8 * HL * WL; // 8 channels of feat
  const long OSTEP  = (long)8 * HH * WH; // 8 channels of out

  float4 t0 = *(const float4*)ps0;
  float4 t1 = *(const float4*)ps1;
  #pragma unroll 1
  for (int k = 0; k < 8; k++) {
    // write current chunk's rows to this wave's LDS region
    *(float4*)&sbuf[s0] = t0;
    *(float4*)&sbuf[s1] = t1;
    // prefetch next chunk (latency hides under compute below)
    if (k < 7) {
      ps0 += CSTEP; ps1 += CSTEP;
      t0 = *(const float4*)ps0;
      t1 = *(const float4*)ps1;
    }
    float v[2][4];
    if (!fb) {
      #pragma unroll
      for (int Yp = 0; Yp < 2; Yp++) {
        #pragma unroll
        for (int j = 0; j < 4; j++) {
          int li = pack[Yp * 4 + j] + ladj;
          float wx = wxa[Yp * 4 + j], wy = wya[Yp * 4 + j];
          float s00 = sbuf[li], s01 = sbuf[li + 1];
          float s10 = sbuf[li + 128], s11 = sbuf[li + 129];
          v[Yp][j] = (s00 * (1.f - wx) + s01 * wx) * (1.f - wy)
                   + (s10 * (1.f - wx) + s11 * wx) * wy;
        }
      }
    } else {
      #pragma unroll
      for (int Yp = 0; Yp < 2; Yp++) {
        #pragma unroll
        for (int j = 0; j < 4; j++) {
          const float* pp = pg + pack[Yp * 4 + j];
          float wx = wxa[Yp * 4 + j], wy = wya[Yp * 4 + j];
          float s00 = pp[0], s01 = pp[1];
          float s10 = pp[WL], s11 = pp[WL + 1];
          v[Yp][j] = (s00 * (1.f - wx) + s01 * wx) * (1.f - wy)
                   + (s10 * (1.f - wx) + s11 * wx) * wy;
        }
      }
    }
    *(float4*)po0 = make_float4(v[0][0], v[0][1], v[0][2], v[0][3]);
    *(float4*)po1 = make_float4(v[1][0], v[1][1], v[1][2], v[1][3]);
    po0 += OSTEP; po1 += OSTEP;
    pg  += CSTEP;
  }
}

extern "C" void kernel_launch(void* const* d_in, const int* in_sizes, int n_in,
                              void* d_out, int out_size, void* d_ws, size_t ws_size,
                              hipStream_t stream) {
  const float* x_l     = (const float*)d_in[0];
  const float* x_h     = (const float*)d_in[1];
  const float* feat    = (const float*)d_in[2];
  const float* gn_l_w  = (const float*)d_in[3];
  const float* gn_l_b  = (const float*)d_in[4];
  const float* gn_h_w  = (const float*)d_in[5];
  const float* gn_h_b  = (const float*)d_in[6];
  const float* w_off   = (const float*)d_in[7];
  const float* s_off   = (const float*)d_in[8];
  const float* b_off   = (const float*)d_in[9];
  const float* w_off_h = (const float*)d_in[10];
  const float* s_off_h = (const float*)d_in[11];
  const float* b_off_h = (const float*)d_in[12];
  const float* w_ds    = (const float*)d_in[13];
  const float* s_ds    = (const float*)d_in[14];
  const float* b_ds    = (const float*)d_in[15];
  const float* w_ds_h  = (const float*)d_in[16];
  const float* s_ds_h  = (const float*)d_in[17];
  const float* b_ds_h  = (const float*)d_in[18];
  float* ws  = (float*)d_ws;
  float* out = (float*)d_out;

  k_stats1<<<1280, 256, 0, stream>>>(x_l, x_h, ws);
  k_stats2<<<32, 64, 0, stream>>>(gn_l_w, gn_l_b, gn_h_w, gn_h_b, ws);
  k_head<HL, WL, 64><<<(BATCH * HL * WL) / 64, 512, 0, stream>>>(
      x_l, w_off, w_ds, s_off, b_off, s_ds, b_ds,
      ws + WS_AL, ws + WS_BL, ws + WS_OFFL, ws + WS_DSL);
  k_head<HH, WH, 16><<<(BATCH * HH * WH) / 64, 512, 0, stream>>>(
      x_h, w_off_h, w_ds_h, s_off_h, b_off_h, s_ds_h, b_ds_h,
      ws + WS_AH, ws + WS_BH, ws + WS_OFFH, ws + WS_DSH);
  k_combine<<<(BATCH * 16 * HL * WL) / 256, 256, 0, stream>>>(ws);
  k_sample<<<BATCH * 4 * HL, 512, 0, stream>>>(feat, ws, out);
}

// Round 10
// 97.977 us; speedup vs baseline: 1.2323x; 1.0130x over previous
//
#include <hip/hip_runtime.h>
#include <math.h>

#define BATCH 2
#define CCH 64      // C
#define HL 128
#define WL 128
#define HH 256
#define WH 256
#define CFCH 256
#define CIN 72

// workspace layout (float offsets) — compact
constexpr long WS_AL   = 0;                     // a_l   (B*C = 128)
constexpr long WS_BL   = 128;                   // bb_l
constexpr long WS_AH   = 256;                   // a_h
constexpr long WS_BH   = 384;                   // bb_h
constexpr long WS_OFFL = 512;                   // 2*32*128*128 = 1048576
constexpr long WS_DSL  = WS_OFFL + 1048576;
constexpr long WS_OFFH = WS_DSL + 1048576;      // 2*8*256*256 = 1048576
constexpr long WS_DSH  = WS_OFFH + 1048576;
constexpr long WS_CRD  = WS_DSH + 1048576;      // float2[2*16*128*128] = 1048576 floats
constexpr long WS_PART = WS_CRD + 1048576;      // 32 groups * 64 slices * 2

// ---------------- K1a: partial sums over 8192-element slices ----------------
__global__ void k_stats1(const float* __restrict__ xl, const float* __restrict__ xh,
                         float* __restrict__ ws) {
  int blk = blockIdx.x;
  const float* x;
  long base;
  int gg, slice;
  if (blk < 256) {
    int g = blk >> 4; slice = blk & 15;
    x = xl; gg = g;
    base = (long)g * 8 * (HL * WL) + (long)slice * 8192;
  } else {
    int id = blk - 256;
    int g = id >> 6; slice = id & 63;
    x = xh; gg = 16 + g;
    base = (long)g * 8 * (HH * WH) + (long)slice * 8192;
  }
  const float4* p = (const float4*)(x + base);
  float s = 0.f, s2 = 0.f;
  #pragma unroll
  for (int k = 0; k < 8; k++) {
    float4 v = p[threadIdx.x + k * 256];
    s  += v.x + v.y + v.z + v.w;
    s2 += v.x * v.x + v.y * v.y + v.z * v.z + v.w * v.w;
  }
  __shared__ float sh1[256], sh2[256];
  sh1[threadIdx.x] = s; sh2[threadIdx.x] = s2;
  __syncthreads();
  for (int off = 128; off > 0; off >>= 1) {
    if (threadIdx.x < off) {
      sh1[threadIdx.x] += sh1[threadIdx.x + off];
      sh2[threadIdx.x] += sh2[threadIdx.x + off];
    }
    __syncthreads();
  }
  if (threadIdx.x == 0) {
    ws[WS_PART + (gg * 64 + slice) * 2]     = sh1[0];
    ws[WS_PART + (gg * 64 + slice) * 2 + 1] = sh2[0];
  }
}

// ---------------- K1b: finalize per-channel affine coefficients -------------
__global__ void k_stats2(const float* __restrict__ gwl, const float* __restrict__ gbl,
                         const float* __restrict__ gwh, const float* __restrict__ gbh,
                         float* __restrict__ ws) {
  int blk = blockIdx.x;          // 0..31
  bool high = blk >= 16;
  int id = blk & 15;
  int b = id >> 3, g = id & 7;
  int gg = high ? 16 + id : id;
  int nsl = high ? 64 : 16;
  long n = high ? (long)8 * HH * WH : (long)8 * HL * WL;
  float s = 0.f, s2 = 0.f;
  for (int i = threadIdx.x; i < nsl; i += 64) {
    s  += ws[WS_PART + (gg * 64 + i) * 2];
    s2 += ws[WS_PART + (gg * 64 + i) * 2 + 1];
  }
  for (int off = 32; off > 0; off >>= 1) {
    s  += __shfl_down(s, off);
    s2 += __shfl_down(s2, off);
  }
  __shared__ float shm[2];
  if (threadIdx.x == 0) { shm[0] = s; shm[1] = s2; }
  __syncthreads();
  if (threadIdx.x < 8) {
    float mean = shm[0] / (float)n;
    float var  = shm[1] / (float)n - mean * mean;
    float inv  = rsqrtf(var + 1e-5f);
    int c = g * 8 + threadIdx.x;
    const float* gw = high ? gwh : gwl;
    const float* gb = high ? gbh : gbl;
    float a  = gw[c] * inv;
    float bb = gb[c] - mean * a;
    float* abase = ws + (high ? WS_AH : WS_AL);
    abase[b * CCH + c] = a;
    abase[128 + b * CCH + c] = bb;
  }
}

// ---------------- K3/K4: fused sim + conv1x1_bn heads ----------------------
template<int HSZ, int WSZ, int NOUT>
__global__ __launch_bounds__(512) void k_head(
                       const float* __restrict__ x,
                       const float* __restrict__ w_off, const float* __restrict__ w_ds,
                       const float* __restrict__ s_off, const float* __restrict__ b_off,
                       const float* __restrict__ s_ds,  const float* __restrict__ b_ds,
                       const float* __restrict__ acoef, const float* __restrict__ bcoef,
                       float* __restrict__ out_off, float* __restrict__ out_ds) {
  constexpr int HW   = HSZ * WSZ;
  constexpr int half = NOUT / 2;
  constexpr int PER  = NOUT / 8;
  __shared__ float wsm[NOUT * CIN];
  __shared__ float xc[CCH * 64];
  __shared__ float psum[8 * 64];
  __shared__ float sims[8 * 64];
  __shared__ float asm_[CCH], bsm_[CCH];

  int tid = threadIdx.x;
  int px = tid & 63;
  int t  = tid >> 6;                 // wave index 0..7, wave-uniform
  int gpix = blockIdx.x * 64 + px;
  int xq = gpix % WSZ;
  int yq = (gpix / WSZ) % HSZ;
  int bq = gpix / (WSZ * HSZ);       // uniform per block

  for (int i = tid; i < NOUT * CIN; i += 512) {
    int o = i / CIN, c = i % CIN;
    wsm[i] = (o < half) ? w_off[o * CIN + c] : w_ds[(o - half) * CIN + c];
  }
  if (tid < CCH)            asm_[tid] = acoef[bq * CCH + tid];
  else if (tid < 2 * CCH)   bsm_[tid - CCH] = bcoef[bq * CCH + tid - CCH];
  __syncthreads();

  const float* ptr = x + ((long)(bq * CCH)) * HW + yq * WSZ + xq;

  // phase 0: center tile + sumsq partials
  {
    float ss = 0.f;
    #pragma unroll
    for (int k = 0; k < 8; k++) {
      int c = t * 8 + k;
      float v = fmaf(asm_[c], ptr[(long)c * HW], bsm_[c]);
      xc[c * 64 + px] = v;
      ss += v * v;
    }
    psum[t * 64 + px] = ss;
  }
  __syncthreads();

  // phase 1: neighbor t
  {
    const int dyv[8] = {-2,-2,-2, 0, 0, 2, 2, 2};
    const int dxv[8] = {-2, 0, 2,-2, 2,-2, 0, 2};
    int dy = dyv[t], dx = dxv[t];
    int yn = yq + dy;                // uniform
    int xn = xq + dx;                // per-lane
    bool ok = (yn >= 0 && yn < HSZ && xn >= 0 && xn < WSZ);
    float dot = 0.f, nbq = 0.f;
    if (ok) {
      const float* nptr = ptr + (long)dy * WSZ + dx;
      #pragma unroll 16
      for (int c = 0; c < CCH; c++) {
        float nb = fmaf(asm_[c], nptr[(long)c * HW], bsm_[c]);
        float xv = xc[c * 64 + px];
        dot += xv * nb;
        nbq += nb * nb;
      }
    }
    float cs = 0.f;
    #pragma unroll
    for (int tt = 0; tt < 8; tt++) cs += psum[tt * 64 + px];
    float cnc = sqrtf(cs);
    sims[t * 64 + px] = dot / fmaxf(cnc * sqrtf(nbq), 1e-8f);
  }
  __syncthreads();

  // phase 2: conv outputs for this wave
  {
    float sv[8];
    #pragma unroll
    for (int j = 0; j < 8; j++) sv[j] = sims[j * 64 + px];
    float acc[PER];
    #pragma unroll
    for (int ol = 0; ol < PER; ol++) acc[ol] = 0.f;
    int o0 = t * PER;
    #pragma unroll 4
    for (int c = 0; c < CCH; c += 4) {
      float x0v = xc[(c + 0) * 64 + px];
      float x1v = xc[(c + 1) * 64 + px];
      float x2v = xc[(c + 2) * 64 + px];
      float x3v = xc[(c + 3) * 64 + px];
      #pragma unroll
      for (int ol = 0; ol < PER; ol++) {
        const float4 w4 = *(const float4*)&wsm[(o0 + ol) * CIN + c];
        acc[ol] += w4.x * x0v + w4.y * x1v + w4.z * x2v + w4.w * x3v;
      }
    }
    #pragma unroll
    for (int ol = 0; ol < PER; ol++) {
      const float4 wa = *(const float4*)&wsm[(o0 + ol) * CIN + 64];
      const float4 wb = *(const float4*)&wsm[(o0 + ol) * CIN + 68];
      acc[ol] += wa.x * sv[0] + wa.y * sv[1] + wa.z * sv[2] + wa.w * sv[3]
               + wb.x * sv[4] + wb.y * sv[5] + wb.z * sv[6] + wb.w * sv[7];
    }
    #pragma unroll
    for (int ol = 0; ol < PER; ol++) {
      int o = o0 + ol;
      float v;
      float* dst;
      int oo;
      if (o < half) { v = acc[ol] * s_off[o] + b_off[o];             dst = out_off; oo = o; }
      else          { v = acc[ol] * s_ds[o - half] + b_ds[o - half]; dst = out_ds;  oo = o - half; }
      dst[((long)(bq * half + oo)) * HW + yq * WSZ + xq] = v;
    }
  }
}

// ---------------- K5: combine -> packed clipped sample coords --------------
// one thread per (b,sub,y,x); writes float2 (gx,gy) ready for bilinear.
__global__ __launch_bounds__(256) void k_combine(float* __restrict__ ws) {
  int idx = blockIdx.x * blockDim.x + threadIdx.x;   // B*16*128*128 = 524288
  int x = idx & 127;
  int y = (idx >> 7) & 127;
  int sub = (idx >> 14) & 15;
  int b = idx >> 18;
  int sdx = sub & 1, sdy = (sub >> 1) & 1;

  const float* offl = ws + WS_OFFL;
  const float* dsl  = ws + WS_DSL;
  const float* offh = ws + WS_OFFH;
  const float* dsh  = ws + WS_DSH;

  int lidx = idx + b * (16 * HL * WL);               // channel sub (of 32)
  float ol0 = offl[lidx],               dl0 = dsl[lidx];
  float ol1 = offl[lidx + 16 * HL * WL], dl1 = dsl[lidx + 16 * HL * WL];
  int Y = 2 * y + sdy, X = 2 * x + sdx;
  long h0 = ((long)(b * 8 + (sub >> 2)) * HH + Y) * WH + X;
  long h1 = h0 + (long)4 * HH * WH;
  float oh0 = offh[h0], dh0 = dsh[h0];
  float oh1 = offh[h1], dh1 = dsh[h1];
  float gate0 = 1.f / (1.f + expf(-(dl0 + dh0)));
  float gate1 = 1.f / (1.f + expf(-(dl1 + dh1)));
  float offx = (ol0 + oh0) * gate0 + (sdx ? 0.25f : -0.25f);
  float offy = (ol1 + oh1) * gate1 + (sdy ? 0.25f : -0.25f);
  float gx = fminf(fmaxf((float)x + offx, 0.f), (float)(WL - 1));
  float gy = fminf(fmaxf((float)y + offy, 0.f), (float)(HL - 1));
  float2* crd = (float2*)(ws + WS_CRD);
  crd[idx] = float2{gx, gy};
}

// ---------------- K6: LDS-staged bilinear sampler --------------------------
// block = (b,g,Y): one fine output row Y (all 256 X), 64 channels.
// 8 waves; wave w privately stages channel (chunk*8+w)'s rows y-1..y+2 into
// its own LDS region (global->reg->LDS, next chunk prefetched during compute),
// then samples from LDS. No __syncthreads (wave-private regions). Outlier
// coords take an exact global-gather fallback (rare; execz-skipped).
// launch_bounds(512,8): 32 waves/CU -> 4 blocks/CU resident; grid 2048 =
// exactly 2 balanced residency rounds (fixes round-9's 3-resident/4-work tail).
__global__ __launch_bounds__(512, 8) void k_sample(const float* __restrict__ feat,
                                                   const float* __restrict__ ws,
                                                   float* __restrict__ out) {
  __shared__ float sbuf[8 * 512];   // 16 KB: [wave][4 rows][128]
  // XCD swizzle: 2048 blocks, 8 XCDs -> each XCD owns one (b,g) feat slab.
  int bid = (blockIdx.x & 7) * 256 + (blockIdx.x >> 3);
  int Y = bid & 255;
  int g = (bid >> 8) & 3;
  int b = bid >> 10;
  int y = Y >> 1, sdy = Y & 1;
  int w = threadIdx.x >> 6;         // wave id = local channel, uniform
  int l = threadIdx.x & 63;         // lane = X-group (4 consecutive X)

  // ---- coords: 4 sets (j = X sub-position), reused for all 64 channels
  const float2* crd = (const float2*)(ws + WS_CRD);
  int   pack[4];
  float wxa[4], wya[4];
  bool fb = false;
  #pragma unroll
  for (int j = 0; j < 4; j++) {
    int X = 4 * l + j;
    int x = X >> 1, sdx = X & 1;
    int sub = 4 * g + 2 * sdy + sdx;
    float2 cc = crd[((long)(b * 16 + sub)) * (HL * WL) + y * WL + x];
    float gx = cc.x, gy = cc.y;
    float fx0 = floorf(gx), fy0 = floorf(gy);
    int x0 = (int)fx0, y0 = (int)fy0;
    float wx = gx - fx0, wy = gy - fy0;
    if (x0 >= WL - 1) { x0 = WL - 2; wx = 1.f; }
    if (y0 >= HL - 1) { y0 = HL - 2; wy = 1.f; }
    fb = fb || (y0 < y - 1) || (y0 > y + 1);
    pack[j] = y0 * WL + x0;
    wxa[j] = wx;
    wya[j] = wy;
  }
  int ladj = w * 512 + (1 - y) * 128;    // lds idx = pack + ladj

  // ---- staging addresses (wave w stages its own channel)
  int row0 = l >> 5;                     // 0/1
  int row1 = 2 + row0;                   // 2/3
  int fr0 = min(max(y - 1 + row0, 0), HL - 1);
  int fr1 = min(max(y - 1 + row1, 0), HL - 1);
  int x4 = (l & 31) * 4;
  long cbase = (long)(b * CFCH + g * 64 + w);
  const float* ps0 = feat + (cbase * HL + fr0) * WL + x4;
  const float* ps1 = feat + (cbase * HL + fr1) * WL + x4;
  const float* pg  = feat + cbase * (HL * WL);
  int s0 = w * 512 + row0 * 128 + x4;
  int s1 = w * 512 + row1 * 128 + x4;
  float* po = out + (cbase * HH + Y) * WH + 4 * l;
  const long CSTEP  = (long)8 * HL * WL; // 8 channels of feat
  const long OSTEP  = (long)8 * HH * WH; // 8 channels of out

  float4 t0 = *(const float4*)ps0;
  float4 t1 = *(const float4*)ps1;
  #pragma unroll 1
  for (int k = 0; k < 8; k++) {
    // write current chunk's rows to this wave's LDS region
    *(float4*)&sbuf[s0] = t0;
    *(float4*)&sbuf[s1] = t1;
    // prefetch next chunk (latency hides under compute below)
    if (k < 7) {
      ps0 += CSTEP; ps1 += CSTEP;
      t0 = *(const float4*)ps0;
      t1 = *(const float4*)ps1;
    }
    float v[4];
    if (!fb) {
      #pragma unroll
      for (int j = 0; j < 4; j++) {
        int li = pack[j] + ladj;
        float wx = wxa[j], wy = wya[j];
        float s00 = sbuf[li], s01 = sbuf[li + 1];
        float s10 = sbuf[li + 128], s11 = sbuf[li + 129];
        v[j] = (s00 * (1.f - wx) + s01 * wx) * (1.f - wy)
             + (s10 * (1.f - wx) + s11 * wx) * wy;
      }
    } else {
      #pragma unroll
      for (int j = 0; j < 4; j++) {
        const float* pp = pg + pack[j];
        float wx = wxa[j], wy = wya[j];
        float s00 = pp[0], s01 = pp[1];
        float s10 = pp[WL], s11 = pp[WL + 1];
        v[j] = (s00 * (1.f - wx) + s01 * wx) * (1.f - wy)
             + (s10 * (1.f - wx) + s11 * wx) * wy;
      }
    }
    *(float4*)po = make_float4(v[0], v[1], v[2], v[3]);
    po += OSTEP;
    pg += CSTEP;
  }
}

extern "C" void kernel_launch(void* const* d_in, const int* in_sizes, int n_in,
                              void* d_out, int out_size, void* d_ws, size_t ws_size,
                              hipStream_t stream) {
  const float* x_l     = (const float*)d_in[0];
  const float* x_h     = (const float*)d_in[1];
  const float* feat    = (const float*)d_in[2];
  const float* gn_l_w  = (const float*)d_in[3];
  const float* gn_l_b  = (const float*)d_in[4];
  const float* gn_h_w  = (const float*)d_in[5];
  const float* gn_h_b  = (const float*)d_in[6];
  const float* w_off   = (const float*)d_in[7];
  const float* s_off   = (const float*)d_in[8];
  const float* b_off   = (const float*)d_in[9];
  const float* w_off_h = (const float*)d_in[10];
  const float* s_off_h = (const float*)d_in[11];
  const float* b_off_h = (const float*)d_in[12];
  const float* w_ds    = (const float*)d_in[13];
  const float* s_ds    = (const float*)d_in[14];
  const float* b_ds    = (const float*)d_in[15];
  const float* w_ds_h  = (const float*)d_in[16];
  const float* s_ds_h  = (const float*)d_in[17];
  const float* b_ds_h  = (const float*)d_in[18];
  float* ws  = (float*)d_ws;
  float* out = (float*)d_out;

  k_stats1<<<1280, 256, 0, stream>>>(x_l, x_h, ws);
  k_stats2<<<32, 64, 0, stream>>>(gn_l_w, gn_l_b, gn_h_w, gn_h_b, ws);
  k_head<HL, WL, 64><<<(BATCH * HL * WL) / 64, 512, 0, stream>>>(
      x_l, w_off, w_ds, s_off, b_off, s_ds, b_ds,
      ws + WS_AL, ws + WS_BL, ws + WS_OFFL, ws + WS_DSL);
  k_head<HH, WH, 16><<<(BATCH * HH * WH) / 64, 512, 0, stream>>>(
      x_h, w_off_h, w_ds_h, s_off_h, b_off_h, s_ds_h, b_ds_h,
      ws + WS_AH, ws + WS_BH, ws + WS_OFFH, ws + WS_DSH);
  k_combine<<<(BATCH * 16 * HL * WL) / 256, 256, 0, stream>>>(ws);
  k_sample<<<BATCH * 4 * HH, 512, 0, stream>>>(feat, ws, out);
}

// Round 11
// 97.824 us; speedup vs baseline: 1.2342x; 1.0016x over previous
//
#include <hip/hip_runtime.h>
#include <math.h>

#define BATCH 2
#define CCH 64      // C
#define HL 128
#define WL 128
#define HH 256
#define WH 256
#define CFCH 256
#define CIN 72

// workspace layout (float offsets) — compact
constexpr long WS_AL   = 0;                     // a_l   (B*C = 128)
constexpr long WS_BL   = 128;                   // bb_l
constexpr long WS_AH   = 256;                   // a_h
constexpr long WS_BH   = 384;                   // bb_h
constexpr long WS_OFFL = 512;                   // 2*32*128*128 = 1048576
constexpr long WS_DSL  = WS_OFFL + 1048576;
constexpr long WS_OFFH = WS_DSL + 1048576;      // 2*8*256*256 = 1048576
constexpr long WS_DSH  = WS_OFFH + 1048576;
constexpr long WS_CRD  = WS_DSH + 1048576;      // float2[2*16*128*128] = 1048576 floats
constexpr long WS_PART = WS_CRD + 1048576;      // 32 groups * 64 slices * 2

// ---------------- K1a: partial sums over 8192-element slices ----------------
__global__ void k_stats1(const float* __restrict__ xl, const float* __restrict__ xh,
                         float* __restrict__ ws) {
  int blk = blockIdx.x;
  const float* x;
  long base;
  int gg, slice;
  if (blk < 256) {
    int g = blk >> 4; slice = blk & 15;
    x = xl; gg = g;
    base = (long)g * 8 * (HL * WL) + (long)slice * 8192;
  } else {
    int id = blk - 256;
    int g = id >> 6; slice = id & 63;
    x = xh; gg = 16 + g;
    base = (long)g * 8 * (HH * WH) + (long)slice * 8192;
  }
  const float4* p = (const float4*)(x + base);
  float s = 0.f, s2 = 0.f;
  #pragma unroll
  for (int k = 0; k < 8; k++) {
    float4 v = p[threadIdx.x + k * 256];
    s  += v.x + v.y + v.z + v.w;
    s2 += v.x * v.x + v.y * v.y + v.z * v.z + v.w * v.w;
  }
  __shared__ float sh1[256], sh2[256];
  sh1[threadIdx.x] = s; sh2[threadIdx.x] = s2;
  __syncthreads();
  for (int off = 128; off > 0; off >>= 1) {
    if (threadIdx.x < off) {
      sh1[threadIdx.x] += sh1[threadIdx.x + off];
      sh2[threadIdx.x] += sh2[threadIdx.x + off];
    }
    __syncthreads();
  }
  if (threadIdx.x == 0) {
    ws[WS_PART + (gg * 64 + slice) * 2]     = sh1[0];
    ws[WS_PART + (gg * 64 + slice) * 2 + 1] = sh2[0];
  }
}

// ---------------- K1b: finalize per-channel affine coefficients -------------
__global__ void k_stats2(const float* __restrict__ gwl, const float* __restrict__ gbl,
                         const float* __restrict__ gwh, const float* __restrict__ gbh,
                         float* __restrict__ ws) {
  int blk = blockIdx.x;          // 0..31
  bool high = blk >= 16;
  int id = blk & 15;
  int b = id >> 3, g = id & 7;
  int gg = high ? 16 + id : id;
  int nsl = high ? 64 : 16;
  long n = high ? (long)8 * HH * WH : (long)8 * HL * WL;
  float s = 0.f, s2 = 0.f;
  for (int i = threadIdx.x; i < nsl; i += 64) {
    s  += ws[WS_PART + (gg * 64 + i) * 2];
    s2 += ws[WS_PART + (gg * 64 + i) * 2 + 1];
  }
  for (int off = 32; off > 0; off >>= 1) {
    s  += __shfl_down(s, off);
    s2 += __shfl_down(s2, off);
  }
  __shared__ float shm[2];
  if (threadIdx.x == 0) { shm[0] = s; shm[1] = s2; }
  __syncthreads();
  if (threadIdx.x < 8) {
    float mean = shm[0] / (float)n;
    float var  = shm[1] / (float)n - mean * mean;
    float inv  = rsqrtf(var + 1e-5f);
    int c = g * 8 + threadIdx.x;
    const float* gw = high ? gwh : gwl;
    const float* gb = high ? gbh : gbl;
    float a  = gw[c] * inv;
    float bb = gb[c] - mean * a;
    float* abase = ws + (high ? WS_AH : WS_AL);
    abase[b * CCH + c] = a;
    abase[128 + b * CCH + c] = bb;
  }
}

// ---------------- K3/K4: fused sim + conv1x1_bn heads ----------------------
// XCD-swizzled: each XCD works a contiguous pixel stripe (~1-4 MB of x) so
// the 9x neighbor re-reads are L2-served.
template<int HSZ, int WSZ, int NOUT>
__global__ __launch_bounds__(512) void k_head(
                       const float* __restrict__ x,
                       const float* __restrict__ w_off, const float* __restrict__ w_ds,
                       const float* __restrict__ s_off, const float* __restrict__ b_off,
                       const float* __restrict__ s_ds,  const float* __restrict__ b_ds,
                       const float* __restrict__ acoef, const float* __restrict__ bcoef,
                       float* __restrict__ out_off, float* __restrict__ out_ds) {
  constexpr int HW   = HSZ * WSZ;
  constexpr int half = NOUT / 2;
  constexpr int PER  = NOUT / 8;
  __shared__ float wsm[NOUT * CIN];
  __shared__ float xc[CCH * 64];
  __shared__ float psum[8 * 64];
  __shared__ float sims[8 * 64];
  __shared__ float asm_[CCH], bsm_[CCH];

  int tid = threadIdx.x;
  int px = tid & 63;
  int t  = tid >> 6;                 // wave index 0..7, wave-uniform
  int bid = (blockIdx.x & 7) * (gridDim.x >> 3) + (blockIdx.x >> 3);
  int gpix = bid * 64 + px;
  int xq = gpix % WSZ;
  int yq = (gpix / WSZ) % HSZ;
  int bq = gpix / (WSZ * HSZ);       // uniform per block

  for (int i = tid; i < NOUT * CIN; i += 512) {
    int o = i / CIN, c = i % CIN;
    wsm[i] = (o < half) ? w_off[o * CIN + c] : w_ds[(o - half) * CIN + c];
  }
  if (tid < CCH)            asm_[tid] = acoef[bq * CCH + tid];
  else if (tid < 2 * CCH)   bsm_[tid - CCH] = bcoef[bq * CCH + tid - CCH];
  __syncthreads();

  const float* ptr = x + ((long)(bq * CCH)) * HW + yq * WSZ + xq;

  // phase 0: center tile + sumsq partials
  {
    float ss = 0.f;
    #pragma unroll
    for (int k = 0; k < 8; k++) {
      int c = t * 8 + k;
      float v = fmaf(asm_[c], ptr[(long)c * HW], bsm_[c]);
      xc[c * 64 + px] = v;
      ss += v * v;
    }
    psum[t * 64 + px] = ss;
  }
  __syncthreads();

  // phase 1: neighbor t
  {
    const int dyv[8] = {-2,-2,-2, 0, 0, 2, 2, 2};
    const int dxv[8] = {-2, 0, 2,-2, 2,-2, 0, 2};
    int dy = dyv[t], dx = dxv[t];
    int yn = yq + dy;                // uniform
    int xn = xq + dx;                // per-lane
    bool ok = (yn >= 0 && yn < HSZ && xn >= 0 && xn < WSZ);
    float dot = 0.f, nbq = 0.f;
    if (ok) {
      const float* nptr = ptr + (long)dy * WSZ + dx;
      #pragma unroll 16
      for (int c = 0; c < CCH; c++) {
        float nb = fmaf(asm_[c], nptr[(long)c * HW], bsm_[c]);
        float xv = xc[c * 64 + px];
        dot += xv * nb;
        nbq += nb * nb;
      }
    }
    float cs = 0.f;
    #pragma unroll
    for (int tt = 0; tt < 8; tt++) cs += psum[tt * 64 + px];
    float cnc = sqrtf(cs);
    sims[t * 64 + px] = dot / fmaxf(cnc * sqrtf(nbq), 1e-8f);
  }
  __syncthreads();

  // phase 2: conv outputs for this wave
  {
    float sv[8];
    #pragma unroll
    for (int j = 0; j < 8; j++) sv[j] = sims[j * 64 + px];
    float acc[PER];
    #pragma unroll
    for (int ol = 0; ol < PER; ol++) acc[ol] = 0.f;
    int o0 = t * PER;
    #pragma unroll 4
    for (int c = 0; c < CCH; c += 4) {
      float x0v = xc[(c + 0) * 64 + px];
      float x1v = xc[(c + 1) * 64 + px];
      float x2v = xc[(c + 2) * 64 + px];
      float x3v = xc[(c + 3) * 64 + px];
      #pragma unroll
      for (int ol = 0; ol < PER; ol++) {
        const float4 w4 = *(const float4*)&wsm[(o0 + ol) * CIN + c];
        acc[ol] += w4.x * x0v + w4.y * x1v + w4.z * x2v + w4.w * x3v;
      }
    }
    #pragma unroll
    for (int ol = 0; ol < PER; ol++) {
      const float4 wa = *(const float4*)&wsm[(o0 + ol) * CIN + 64];
      const float4 wb = *(const float4*)&wsm[(o0 + ol) * CIN + 68];
      acc[ol] += wa.x * sv[0] + wa.y * sv[1] + wa.z * sv[2] + wa.w * sv[3]
               + wb.x * sv[4] + wb.y * sv[5] + wb.z * sv[6] + wb.w * sv[7];
    }
    #pragma unroll
    for (int ol = 0; ol < PER; ol++) {
      int o = o0 + ol;
      float v;
      float* dst;
      int oo;
      if (o < half) { v = acc[ol] * s_off[o] + b_off[o];             dst = out_off; oo = o; }
      else          { v = acc[ol] * s_ds[o - half] + b_ds[o - half]; dst = out_ds;  oo = o - half; }
      dst[((long)(bq * half + oo)) * HW + yq * WSZ + xq] = v;
    }
  }
}

// ---------------- K5: combine -> packed clipped sample coords --------------
// one thread per (b,sub,y,x); writes float2 (gx,gy) ready for bilinear.
__global__ __launch_bounds__(256) void k_combine(float* __restrict__ ws) {
  int idx = blockIdx.x * blockDim.x + threadIdx.x;   // B*16*128*128 = 524288
  int x = idx & 127;
  int y = (idx >> 7) & 127;
  int sub = (idx >> 14) & 15;
  int b = idx >> 18;
  int sdx = sub & 1, sdy = (sub >> 1) & 1;

  const float* offl = ws + WS_OFFL;
  const float* dsl  = ws + WS_DSL;
  const float* offh = ws + WS_OFFH;
  const float* dsh  = ws + WS_DSH;

  int lidx = idx + b * (16 * HL * WL);               // channel sub (of 32)
  float ol0 = offl[lidx],               dl0 = dsl[lidx];
  float ol1 = offl[lidx + 16 * HL * WL], dl1 = dsl[lidx + 16 * HL * WL];
  int Y = 2 * y + sdy, X = 2 * x + sdx;
  long h0 = ((long)(b * 8 + (sub >> 2)) * HH + Y) * WH + X;
  long h1 = h0 + (long)4 * HH * WH;
  float oh0 = offh[h0], dh0 = dsh[h0];
  float oh1 = offh[h1], dh1 = dsh[h1];
  float gate0 = 1.f / (1.f + expf(-(dl0 + dh0)));
  float gate1 = 1.f / (1.f + expf(-(dl1 + dh1)));
  float offx = (ol0 + oh0) * gate0 + (sdx ? 0.25f : -0.25f);
  float offy = (ol1 + oh1) * gate1 + (sdy ? 0.25f : -0.25f);
  float gx = fminf(fmaxf((float)x + offx, 0.f), (float)(WL - 1));
  float gy = fminf(fmaxf((float)y + offy, 0.f), (float)(HL - 1));
  float2* crd = (float2*)(ws + WS_CRD);
  crd[idx] = float2{gx, gy};
}

// ---------------- K6: LDS-staged bilinear sampler --------------------------
// block = (b,g,ch-half,Y): one fine output row Y (256 px) x 32 channels.
// 4 waves; wave w owns channels chh*32+w*8..+8, stages each channel's rows
// y-1..y+2 into its private LDS region (next channel prefetched during
// compute), samples from LDS. No __syncthreads. Exact global fallback for
// outlier coords (execz-skipped).
// KEY: per-XCD feat working set is a 32-channel half-slab = 2.1 MB -> L2-fit
// (4.19 MB full slab thrashed vs 4 MB L2 + write stream in rounds 8-10).
// Swizzle gives XCD k slabs {2k,2k+1} processed sequentially.
__global__ __launch_bounds__(256, 8) void k_sample(const float* __restrict__ feat,
                                                   const float* __restrict__ ws,
                                                   float* __restrict__ out) {
  __shared__ float sbuf[4 * 512];   // 8 KB: [wave][4 rows][128]
  int bid = (blockIdx.x & 7) * 512 + (blockIdx.x >> 3);  // 4096 blocks
  int Y = bid & 255;
  int slab = bid >> 8;              // 0..15 = (b,g,chh)
  int chh = slab & 1;
  int g = (slab >> 1) & 3;
  int b = slab >> 3;
  int y = Y >> 1, sdy = Y & 1;
  int w = threadIdx.x >> 6;         // wave id 0..3, uniform
  int l = threadIdx.x & 63;         // lane = X-group (4 consecutive X)

  // ---- coords: 4 sets (j = X sub-position), reused for all 32 channels
  const float2* crd = (const float2*)(ws + WS_CRD);
  int   pack[4];
  float wxa[4], wya[4];
  bool fb = false;
  #pragma unroll
  for (int j = 0; j < 4; j++) {
    int X = 4 * l + j;
    int x = X >> 1, sdx = X & 1;
    int sub = 4 * g + 2 * sdy + sdx;
    float2 cc = crd[((long)(b * 16 + sub)) * (HL * WL) + y * WL + x];
    float gx = cc.x, gy = cc.y;
    float fx0 = floorf(gx), fy0 = floorf(gy);
    int x0 = (int)fx0, y0 = (int)fy0;
    float wx = gx - fx0, wy = gy - fy0;
    if (x0 >= WL - 1) { x0 = WL - 2; wx = 1.f; }
    if (y0 >= HL - 1) { y0 = HL - 2; wy = 1.f; }
    fb = fb || (y0 < y - 1) || (y0 > y + 1);
    pack[j] = y0 * WL + x0;
    wxa[j] = wx;
    wya[j] = wy;
  }
  int ladj = w * 512 + (1 - y) * 128;    // lds idx = pack + ladj

  // ---- staging addresses (wave w stages its own channel per chunk)
  int row0 = l >> 5;                     // 0/1
  int row1 = 2 + row0;                   // 2/3
  int fr0 = min(max(y - 1 + row0, 0), HL - 1);
  int fr1 = min(max(y - 1 + row1, 0), HL - 1);
  int x4 = (l & 31) * 4;
  long cbase = (long)(b * CFCH + g * 64 + chh * 32 + w * 8);
  const float* ps0 = feat + (cbase * HL + fr0) * WL + x4;
  const float* ps1 = feat + (cbase * HL + fr1) * WL + x4;
  const float* pg  = feat + cbase * (HL * WL);
  int s0 = w * 512 + row0 * 128 + x4;
  int s1 = w * 512 + row1 * 128 + x4;
  float* po = out + (cbase * HH + Y) * WH + 4 * l;
  const long CSTEP  = (long)HL * WL;     // 1 channel of feat
  const long OSTEP  = (long)HH * WH;     // 1 channel of out

  float4 t0 = *(const float4*)ps0;
  float4 t1 = *(const float4*)ps1;
  #pragma unroll 1
  for (int k = 0; k < 8; k++) {
    // write current channel's rows to this wave's LDS region
    *(float4*)&sbuf[s0] = t0;
    *(float4*)&sbuf[s1] = t1;
    // prefetch next channel (latency hides under compute below)
    if (k < 7) {
      ps0 += CSTEP; ps1 += CSTEP;
      t0 = *(const float4*)ps0;
      t1 = *(const float4*)ps1;
    }
    float v[4];
    if (!fb) {
      #pragma unroll
      for (int j = 0; j < 4; j++) {
        int li = pack[j] + ladj;
        float wx = wxa[j], wy = wya[j];
        float s00 = sbuf[li], s01 = sbuf[li + 1];
        float s10 = sbuf[li + 128], s11 = sbuf[li + 129];
        v[j] = (s00 * (1.f - wx) + s01 * wx) * (1.f - wy)
             + (s10 * (1.f - wx) + s11 * wx) * wy;
      }
    } else {
      #pragma unroll
      for (int j = 0; j < 4; j++) {
        const float* pp = pg + pack[j];
        float wx = wxa[j], wy = wya[j];
        float s00 = pp[0], s01 = pp[1];
        float s10 = pp[WL], s11 = pp[WL + 1];
        v[j] = (s00 * (1.f - wx) + s01 * wx) * (1.f - wy)
             + (s10 * (1.f - wx) + s11 * wx) * wy;
      }
    }
    *(float4*)po = make_float4(v[0], v[1], v[2], v[3]);
    po += OSTEP;
    pg += CSTEP;
  }
}

extern "C" void kernel_launch(void* const* d_in, const int* in_sizes, int n_in,
                              void* d_out, int out_size, void* d_ws, size_t ws_size,
                              hipStream_t stream) {
  const float* x_l     = (const float*)d_in[0];
  const float* x_h     = (const float*)d_in[1];
  const float* feat    = (const float*)d_in[2];
  const float* gn_l_w  = (const float*)d_in[3];
  const float* gn_l_b  = (const float*)d_in[4];
  const float* gn_h_w  = (const float*)d_in[5];
  const float* gn_h_b  = (const float*)d_in[6];
  const float* w_off   = (const float*)d_in[7];
  const float* s_off   = (const float*)d_in[8];
  const float* b_off   = (const float*)d_in[9];
  const float* w_off_h = (const float*)d_in[10];
  const float* s_off_h = (const float*)d_in[11];
  const float* b_off_h = (const float*)d_in[12];
  const float* w_ds    = (const float*)d_in[13];
  const float* s_ds    = (const float*)d_in[14];
  const float* b_ds    = (const float*)d_in[15];
  const float* w_ds_h  = (const float*)d_in[16];
  const float* s_ds_h  = (const float*)d_in[17];
  const float* b_ds_h  = (const float*)d_in[18];
  float* ws  = (float*)d_ws;
  float* out = (float*)d_out;

  k_stats1<<<1280, 256, 0, stream>>>(x_l, x_h, ws);
  k_stats2<<<32, 64, 0, stream>>>(gn_l_w, gn_l_b, gn_h_w, gn_h_b, ws);
  k_head<HL, WL, 64><<<(BATCH * HL * WL) / 64, 512, 0, stream>>>(
      x_l, w_off, w_ds, s_off, b_off, s_ds, b_ds,
      ws + WS_AL, ws + WS_BL, ws + WS_OFFL, ws + WS_DSL);
  k_head<HH, WH, 16><<<(BATCH * HH * WH) / 64, 512, 0, stream>>>(
      x_h, w_off_h, w_ds_h, s_off_h, b_off_h, s_ds_h, b_ds_h,
      ws + WS_AH, ws + WS_BH, ws + WS_OFFH, ws + WS_DSH);
  k_combine<<<(BATCH * 16 * HL * WL) / 256, 256, 0, stream>>>(ws);
  k_sample<<<16 * HH, 256, 0, stream>>>(feat, ws, out);
}

// Round 12
// 94.394 us; speedup vs baseline: 1.2790x; 1.0363x over previous
//
#include <hip/hip_runtime.h>
#include <math.h>

#define BATCH 2
#define CCH 64      // C
#define HL 128
#define WL 128
#define HH 256
#define WH 256
#define CFCH 256
#define CIN 72

// workspace layout (float offsets) — compact
constexpr long WS_AL   = 0;                     // a_l   (B*C = 128)
constexpr long WS_BL   = 128;                   // bb_l
constexpr long WS_AH   = 256;                   // a_h
constexpr long WS_BH   = 384;                   // bb_h
constexpr long WS_OFFL = 512;                   // 2*32*128*128 = 1048576
constexpr long WS_DSL  = WS_OFFL + 1048576;
constexpr long WS_OFFH = WS_DSL + 1048576;      // 2*8*256*256 = 1048576
constexpr long WS_DSH  = WS_OFFH + 1048576;
constexpr long WS_CRD  = WS_DSH + 1048576;      // float2[2*16*128*128] = 1048576 floats
constexpr long WS_PART = WS_CRD + 1048576;      // 32 groups * 64 slices * 2

// ---------------- K1a: partial sums over 8192-element slices ----------------
__global__ void k_stats1(const float* __restrict__ xl, const float* __restrict__ xh,
                         float* __restrict__ ws) {
  int blk = blockIdx.x;
  const float* x;
  long base;
  int gg, slice;
  if (blk < 256) {
    int g = blk >> 4; slice = blk & 15;
    x = xl; gg = g;
    base = (long)g * 8 * (HL * WL) + (long)slice * 8192;
  } else {
    int id = blk - 256;
    int g = id >> 6; slice = id & 63;
    x = xh; gg = 16 + g;
    base = (long)g * 8 * (HH * WH) + (long)slice * 8192;
  }
  const float4* p = (const float4*)(x + base);
  float s = 0.f, s2 = 0.f;
  #pragma unroll
  for (int k = 0; k < 8; k++) {
    float4 v = p[threadIdx.x + k * 256];
    s  += v.x + v.y + v.z + v.w;
    s2 += v.x * v.x + v.y * v.y + v.z * v.z + v.w * v.w;
  }
  __shared__ float sh1[256], sh2[256];
  sh1[threadIdx.x] = s; sh2[threadIdx.x] = s2;
  __syncthreads();
  for (int off = 128; off > 0; off >>= 1) {
    if (threadIdx.x < off) {
      sh1[threadIdx.x] += sh1[threadIdx.x + off];
      sh2[threadIdx.x] += sh2[threadIdx.x + off];
    }
    __syncthreads();
  }
  if (threadIdx.x == 0) {
    ws[WS_PART + (gg * 64 + slice) * 2]     = sh1[0];
    ws[WS_PART + (gg * 64 + slice) * 2 + 1] = sh2[0];
  }
}

// ---------------- K1b: finalize per-channel affine coefficients -------------
__global__ void k_stats2(const float* __restrict__ gwl, const float* __restrict__ gbl,
                         const float* __restrict__ gwh, const float* __restrict__ gbh,
                         float* __restrict__ ws) {
  int blk = blockIdx.x;          // 0..31
  bool high = blk >= 16;
  int id = blk & 15;
  int b = id >> 3, g = id & 7;
  int gg = high ? 16 + id : id;
  int nsl = high ? 64 : 16;
  long n = high ? (long)8 * HH * WH : (long)8 * HL * WL;
  float s = 0.f, s2 = 0.f;
  for (int i = threadIdx.x; i < nsl; i += 64) {
    s  += ws[WS_PART + (gg * 64 + i) * 2];
    s2 += ws[WS_PART + (gg * 64 + i) * 2 + 1];
  }
  for (int off = 32; off > 0; off >>= 1) {
    s  += __shfl_down(s, off);
    s2 += __shfl_down(s2, off);
  }
  __shared__ float shm[2];
  if (threadIdx.x == 0) { shm[0] = s; shm[1] = s2; }
  __syncthreads();
  if (threadIdx.x < 8) {
    float mean = shm[0] / (float)n;
    float var  = shm[1] / (float)n - mean * mean;
    float inv  = rsqrtf(var + 1e-5f);
    int c = g * 8 + threadIdx.x;
    const float* gw = high ? gwh : gwl;
    const float* gb = high ? gbh : gbl;
    float a  = gw[c] * inv;
    float bb = gb[c] - mean * a;
    float* abase = ws + (high ? WS_AH : WS_AL);
    abase[b * CCH + c] = a;
    abase[128 + b * CCH + c] = bb;
  }
}

// ---------------- K3: merged sim + conv1x1_bn heads (both resolutions) -----
// One launch: blocks [0,512) = low res, [512,2560) = high res. Shared LDS
// buffer carved per-instantiation (max 9856 floats = 39.4 KB -> 4 blocks/CU).
__device__ __forceinline__ int head_swz(int blk, int n) {
  return (blk & 7) * (n >> 3) + (blk >> 3);
}

template<int HSZ, int WSZ, int NOUT>
__device__ __forceinline__ void head_body(
                       int bid, float* smem,
                       const float* __restrict__ x,
                       const float* __restrict__ w_off, const float* __restrict__ w_ds,
                       const float* __restrict__ s_off, const float* __restrict__ b_off,
                       const float* __restrict__ s_ds,  const float* __restrict__ b_ds,
                       const float* __restrict__ acoef, const float* __restrict__ bcoef,
                       float* __restrict__ out_off, float* __restrict__ out_ds) {
  constexpr int HW   = HSZ * WSZ;
  constexpr int half = NOUT / 2;
  constexpr int PER  = NOUT / 8;
  float* wsm  = smem;                    // NOUT*CIN
  float* xc   = wsm + NOUT * CIN;        // 64*64
  float* psum = xc + CCH * 64;           // 8*64
  float* sims = psum + 512;              // 8*64
  float* asm_ = sims + 512;              // 64
  float* bsm_ = asm_ + 64;               // 64

  int tid = threadIdx.x;
  int px = tid & 63;
  int t  = tid >> 6;                 // wave index 0..7, wave-uniform
  int gpix = bid * 64 + px;
  int xq = gpix % WSZ;
  int yq = (gpix / WSZ) % HSZ;
  int bq = gpix / (WSZ * HSZ);       // uniform per block

  for (int i = tid; i < NOUT * CIN; i += 512) {
    int o = i / CIN, c = i % CIN;
    wsm[i] = (o < half) ? w_off[o * CIN + c] : w_ds[(o - half) * CIN + c];
  }
  if (tid < CCH)            asm_[tid] = acoef[bq * CCH + tid];
  else if (tid < 2 * CCH)   bsm_[tid - CCH] = bcoef[bq * CCH + tid - CCH];
  __syncthreads();

  const float* ptr = x + ((long)(bq * CCH)) * HW + yq * WSZ + xq;

  // phase 0: center tile + sumsq partials
  {
    float ss = 0.f;
    #pragma unroll
    for (int k = 0; k < 8; k++) {
      int c = t * 8 + k;
      float v = fmaf(asm_[c], ptr[(long)c * HW], bsm_[c]);
      xc[c * 64 + px] = v;
      ss += v * v;
    }
    psum[t * 64 + px] = ss;
  }
  __syncthreads();

  // phase 1: neighbor t
  {
    const int dyv[8] = {-2,-2,-2, 0, 0, 2, 2, 2};
    const int dxv[8] = {-2, 0, 2,-2, 2,-2, 0, 2};
    int dy = dyv[t], dx = dxv[t];
    int yn = yq + dy;                // uniform
    int xn = xq + dx;                // per-lane
    bool ok = (yn >= 0 && yn < HSZ && xn >= 0 && xn < WSZ);
    float dot = 0.f, nbq = 0.f;
    if (ok) {
      const float* nptr = ptr + (long)dy * WSZ + dx;
      #pragma unroll 16
      for (int c = 0; c < CCH; c++) {
        float nb = fmaf(asm_[c], nptr[(long)c * HW], bsm_[c]);
        float xv = xc[c * 64 + px];
        dot += xv * nb;
        nbq += nb * nb;
      }
    }
    float cs = 0.f;
    #pragma unroll
    for (int tt = 0; tt < 8; tt++) cs += psum[tt * 64 + px];
    float cnc = sqrtf(cs);
    sims[t * 64 + px] = dot / fmaxf(cnc * sqrtf(nbq), 1e-8f);
  }
  __syncthreads();

  // phase 2: conv outputs for this wave
  {
    float sv[8];
    #pragma unroll
    for (int j = 0; j < 8; j++) sv[j] = sims[j * 64 + px];
    float acc[PER];
    #pragma unroll
    for (int ol = 0; ol < PER; ol++) acc[ol] = 0.f;
    int o0 = t * PER;
    #pragma unroll 4
    for (int c = 0; c < CCH; c += 4) {
      float x0v = xc[(c + 0) * 64 + px];
      float x1v = xc[(c + 1) * 64 + px];
      float x2v = xc[(c + 2) * 64 + px];
      float x3v = xc[(c + 3) * 64 + px];
      #pragma unroll
      for (int ol = 0; ol < PER; ol++) {
        const float4 w4 = *(const float4*)&wsm[(o0 + ol) * CIN + c];
        acc[ol] += w4.x * x0v + w4.y * x1v + w4.z * x2v + w4.w * x3v;
      }
    }
    #pragma unroll
    for (int ol = 0; ol < PER; ol++) {
      const float4 wa = *(const float4*)&wsm[(o0 + ol) * CIN + 64];
      const float4 wb = *(const float4*)&wsm[(o0 + ol) * CIN + 68];
      acc[ol] += wa.x * sv[0] + wa.y * sv[1] + wa.z * sv[2] + wa.w * sv[3]
               + wb.x * sv[4] + wb.y * sv[5] + wb.z * sv[6] + wb.w * sv[7];
    }
    #pragma unroll
    for (int ol = 0; ol < PER; ol++) {
      int o = o0 + ol;
      float v;
      float* dst;
      int oo;
      if (o < half) { v = acc[ol] * s_off[o] + b_off[o];             dst = out_off; oo = o; }
      else          { v = acc[ol] * s_ds[o - half] + b_ds[o - half]; dst = out_ds;  oo = o - half; }
      dst[((long)(bq * half + oo)) * HW + yq * WSZ + xq] = v;
    }
  }
}

__global__ __launch_bounds__(512) void k_heads(
    const float* __restrict__ xl, const float* __restrict__ xh,
    const float* __restrict__ w_off,   const float* __restrict__ w_ds,
    const float* __restrict__ s_off,   const float* __restrict__ b_off,
    const float* __restrict__ s_ds,    const float* __restrict__ b_ds,
    const float* __restrict__ w_off_h, const float* __restrict__ w_ds_h,
    const float* __restrict__ s_off_h, const float* __restrict__ b_off_h,
    const float* __restrict__ s_ds_h,  const float* __restrict__ b_ds_h,
    float* __restrict__ ws) {
  __shared__ float smem[9856];   // max(low: 9856, high: 6400) floats
  if (blockIdx.x < 512) {
    int bid = head_swz(blockIdx.x, 512);
    head_body<HL, WL, 64>(bid, smem, xl, w_off, w_ds, s_off, b_off, s_ds, b_ds,
                          ws + WS_AL, ws + WS_BL, ws + WS_OFFL, ws + WS_DSL);
  } else {
    int bid = head_swz(blockIdx.x - 512, 2048);
    head_body<HH, WH, 16>(bid, smem, xh, w_off_h, w_ds_h, s_off_h, b_off_h,
                          s_ds_h, b_ds_h,
                          ws + WS_AH, ws + WS_BH, ws + WS_OFFH, ws + WS_DSH);
  }
}

// ---------------- K5: combine -> packed clipped sample coords --------------
__global__ __launch_bounds__(256) void k_combine(float* __restrict__ ws) {
  int idx = blockIdx.x * blockDim.x + threadIdx.x;   // B*16*128*128 = 524288
  int x = idx & 127;
  int y = (idx >> 7) & 127;
  int sub = (idx >> 14) & 15;
  int b = idx >> 18;
  int sdx = sub & 1, sdy = (sub >> 1) & 1;

  const float* offl = ws + WS_OFFL;
  const float* dsl  = ws + WS_DSL;
  const float* offh = ws + WS_OFFH;
  const float* dsh  = ws + WS_DSH;

  int lidx = idx + b * (16 * HL * WL);               // channel sub (of 32)
  float ol0 = offl[lidx],               dl0 = dsl[lidx];
  float ol1 = offl[lidx + 16 * HL * WL], dl1 = dsl[lidx + 16 * HL * WL];
  int Y = 2 * y + sdy, X = 2 * x + sdx;
  long h0 = ((long)(b * 8 + (sub >> 2)) * HH + Y) * WH + X;
  long h1 = h0 + (long)4 * HH * WH;
  float oh0 = offh[h0], dh0 = dsh[h0];
  float oh1 = offh[h1], dh1 = dsh[h1];
  float gate0 = 1.f / (1.f + expf(-(dl0 + dh0)));
  float gate1 = 1.f / (1.f + expf(-(dl1 + dh1)));
  float offx = (ol0 + oh0) * gate0 + (sdx ? 0.25f : -0.25f);
  float offy = (ol1 + oh1) * gate1 + (sdy ? 0.25f : -0.25f);
  float gx = fminf(fmaxf((float)x + offx, 0.f), (float)(WL - 1));
  float gy = fminf(fmaxf((float)y + offy, 0.f), (float)(HL - 1));
  float2* crd = (float2*)(ws + WS_CRD);
  crd[idx] = float2{gx, gy};
}

// ---------------- K6: LDS-staged bilinear sampler --------------------------
// block = (b,g,chh,y): BOTH fine rows Y=2y,2y+1 (they share staged rows
// y-1..y+2), 32 channels. 4 waves, wave w owns 8 channels sequentially,
// wave-private LDS staging with next-channel prefetch. Halves staging and
// coord traffic vs one-fine-row blocks. Exact global fallback for outliers.
__global__ __launch_bounds__(256) void k_sample(const float* __restrict__ feat,
                                                const float* __restrict__ ws,
                                                float* __restrict__ out) {
  __shared__ float sbuf[4 * 512];   // 8 KB: [wave][4 rows][128]
  int bid = (blockIdx.x & 7) * 256 + (blockIdx.x >> 3);  // 2048 blocks
  int y = bid & 127;
  int slab = bid >> 7;              // 0..15 = (b,g,chh)
  int chh = slab & 1;
  int g = (slab >> 1) & 3;
  int b = slab >> 3;
  int w = threadIdx.x >> 6;         // wave id 0..3, uniform
  int l = threadIdx.x & 63;         // lane = X-group (4 consecutive X)

  // ---- coords: 8 sets (2 fine rows x 4 X sub-positions), reused for 32 ch
  const float2* crd = (const float2*)(ws + WS_CRD);
  int   pack[8];
  float wxa[8], wya[8];
  bool fb = false;
  #pragma unroll
  for (int sdy = 0; sdy < 2; sdy++) {
    #pragma unroll
    for (int j = 0; j < 4; j++) {
      int X = 4 * l + j;
      int x = X >> 1, sdx = X & 1;
      int sub = 4 * g + 2 * sdy + sdx;
      float2 cc = crd[((long)(b * 16 + sub)) * (HL * WL) + y * WL + x];
      float gx = cc.x, gy = cc.y;
      float fx0 = floorf(gx), fy0 = floorf(gy);
      int x0 = (int)fx0, y0 = (int)fy0;
      float wx = gx - fx0, wy = gy - fy0;
      if (x0 >= WL - 1) { x0 = WL - 2; wx = 1.f; }
      if (y0 >= HL - 1) { y0 = HL - 2; wy = 1.f; }
      fb = fb || (y0 < y - 1) || (y0 > y + 1);
      pack[sdy * 4 + j] = y0 * WL + x0;
      wxa[sdy * 4 + j] = wx;
      wya[sdy * 4 + j] = wy;
    }
  }
  int ladj = w * 512 + (1 - y) * 128;    // lds idx = pack + ladj

  // ---- staging addresses (wave w stages its own channel per chunk)
  int row0 = l >> 5;                     // 0/1
  int row1 = 2 + row0;                   // 2/3
  int fr0 = min(max(y - 1 + row0, 0), HL - 1);
  int fr1 = min(max(y - 1 + row1, 0), HL - 1);
  int x4 = (l & 31) * 4;
  long cbase = (long)(b * CFCH + g * 64 + chh * 32 + w * 8);
  const float* ps0 = feat + (cbase * HL + fr0) * WL + x4;
  const float* ps1 = feat + (cbase * HL + fr1) * WL + x4;
  const float* pg  = feat + cbase * (HL * WL);
  int s0 = w * 512 + row0 * 128 + x4;
  int s1 = w * 512 + row1 * 128 + x4;
  float* po0 = out + (cbase * HH + 2 * y) * WH + 4 * l;
  float* po1 = po0 + WH;
  const long CSTEP  = (long)HL * WL;     // 1 channel of feat
  const long OSTEP  = (long)HH * WH;     // 1 channel of out

  float4 t0 = *(const float4*)ps0;
  float4 t1 = *(const float4*)ps1;
  #pragma unroll 1
  for (int k = 0; k < 8; k++) {
    // write current channel's rows to this wave's LDS region
    *(float4*)&sbuf[s0] = t0;
    *(float4*)&sbuf[s1] = t1;
    // prefetch next channel (latency hides under compute below)
    if (k < 7) {
      ps0 += CSTEP; ps1 += CSTEP;
      t0 = *(const float4*)ps0;
      t1 = *(const float4*)ps1;
    }
    float v[8];
    if (!fb) {
      #pragma unroll
      for (int q = 0; q < 8; q++) {
        int li = pack[q] + ladj;
        float wx = wxa[q], wy = wya[q];
        float s00 = sbuf[li], s01 = sbuf[li + 1];
        float s10 = sbuf[li + 128], s11 = sbuf[li + 129];
        v[q] = (s00 * (1.f - wx) + s01 * wx) * (1.f - wy)
             + (s10 * (1.f - wx) + s11 * wx) * wy;
      }
    } else {
      #pragma unroll
      for (int q = 0; q < 8; q++) {
        const float* pp = pg + pack[q];
        float wx = wxa[q], wy = wya[q];
        float s00 = pp[0], s01 = pp[1];
        float s10 = pp[WL], s11 = pp[WL + 1];
        v[q] = (s00 * (1.f - wx) + s01 * wx) * (1.f - wy)
             + (s10 * (1.f - wx) + s11 * wx) * wy;
      }
    }
    *(float4*)po0 = make_float4(v[0], v[1], v[2], v[3]);
    *(float4*)po1 = make_float4(v[4], v[5], v[6], v[7]);
    po0 += OSTEP; po1 += OSTEP;
    pg += CSTEP;
  }
}

extern "C" void kernel_launch(void* const* d_in, const int* in_sizes, int n_in,
                              void* d_out, int out_size, void* d_ws, size_t ws_size,
                              hipStream_t stream) {
  const float* x_l     = (const float*)d_in[0];
  const float* x_h     = (const float*)d_in[1];
  const float* feat    = (const float*)d_in[2];
  const float* gn_l_w  = (const float*)d_in[3];
  const float* gn_l_b  = (const float*)d_in[4];
  const float* gn_h_w  = (const float*)d_in[5];
  const float* gn_h_b  = (const float*)d_in[6];
  const float* w_off   = (const float*)d_in[7];
  const float* s_off   = (const float*)d_in[8];
  const float* b_off   = (const float*)d_in[9];
  const float* w_off_h = (const float*)d_in[10];
  const float* s_off_h = (const float*)d_in[11];
  const float* b_off_h = (const float*)d_in[12];
  const float* w_ds    = (const float*)d_in[13];
  const float* s_ds    = (const float*)d_in[14];
  const float* b_ds    = (const float*)d_in[15];
  const float* w_ds_h  = (const float*)d_in[16];
  const float* s_ds_h  = (const float*)d_in[17];
  const float* b_ds_h  = (const float*)d_in[18];
  float* ws  = (float*)d_ws;
  float* out = (float*)d_out;

  k_stats1<<<1280, 256, 0, stream>>>(x_l, x_h, ws);
  k_stats2<<<32, 64, 0, stream>>>(gn_l_w, gn_l_b, gn_h_w, gn_h_b, ws);
  k_heads<<<2560, 512, 0, stream>>>(x_l, x_h,
      w_off, w_ds, s_off, b_off, s_ds, b_ds,
      w_off_h, w_ds_h, s_off_h, b_off_h, s_ds_h, b_ds_h, ws);
  k_combine<<<(BATCH * 16 * HL * WL) / 256, 256, 0, stream>>>(ws);
  k_sample<<<2048, 256, 0, stream>>>(feat, ws, out);
}